// Round 1
// baseline (313.613 us; speedup 1.0000x reference)
//
#include <hip/hip_runtime.h>
#include <hip/hip_bf16.h>
#include <math.h>

// MoLE layer: out = gelu(x @ base_w^T + base_b) + top1_w * (gelu(x @ A[e]) @ B[e])
// probs = softmax(x @ gate_w^T + gate_b)
// T=8192 tokens, D=2048, E=8 experts, RANK=16.
//
// Strategy:
//  k1 cvt:    fp32->bf16 convert x (33.5MB) and base_w (8.4MB); transpose lora_B
//             into Bt[j][e*16+r] bf16 (K-major for MFMA B-operand).
//  k2 router: per-token (1 block/token) logits+softmax+argmax in exact fp32,
//             probs -> d_out tail; A''[t][e*16+r] = one-hot-expanded w*gelu(h) bf16.
//  k3 gemm:   m97-structure 128x128 bf16 MFMA GEMM (global_load_lds width=16,
//             BK=32, 4 waves x 4x4 accs). Epilogue: +bias, tanh-GELU, then the
//             LoRA as 4 more K=32 MFMA steps (K_lora=128) from A''/Bt, store fp32.

#define DIM   2048
#define RANK  16
#define NEXP  8
#define NTOK  8192
#define KLORA 128   // NEXP*RANK

typedef __hip_bfloat16 bf16;
typedef __attribute__((ext_vector_type(8))) short short8;  // 8 bf16 = 4 VGPRs
typedef __attribute__((ext_vector_type(4))) float float4v;

typedef const __attribute__((address_space(1))) void* gptr_t;
typedef __attribute__((address_space(3))) void*       sptr_t;

__device__ __forceinline__ void async_ld16(const bf16* g, bf16* l) {
    // wave-uniform LDS base + lane*16B; per-lane global address
    __builtin_amdgcn_global_load_lds((gptr_t)g, (sptr_t)l, 16, 0, 0);
}

// tanh-approx GELU: |err vs erf-gelu| <= ~3e-3, well under 0.1 threshold
__device__ __forceinline__ float gelu_fast(float x) {
    float t = 0.7978845608028654f * (x + 0.044715f * x * x * x);
    t = fminf(fmaxf(t, -10.0f), 10.0f);           // avoid inf/inf
    float e = __expf(2.0f * t);
    float th = (e - 1.0f) / (e + 1.0f);
    return 0.5f * x * (1.0f + th);
}

__device__ __forceinline__ float gelu_exact(float x) {
    return 0.5f * x * (1.0f + erff(x * 0.7071067811865475f));
}

__device__ __forceinline__ short8 pack8(float4 v0, float4 v1) {
    union { bf16 h[8]; short8 v; } u;
    u.h[0] = __float2bfloat16(v0.x); u.h[1] = __float2bfloat16(v0.y);
    u.h[2] = __float2bfloat16(v0.z); u.h[3] = __float2bfloat16(v0.w);
    u.h[4] = __float2bfloat16(v1.x); u.h[5] = __float2bfloat16(v1.y);
    u.h[6] = __float2bfloat16(v1.z); u.h[7] = __float2bfloat16(v1.w);
    return u.v;
}

// ---------------------------------------------------------------- cvt kernel
__global__ __launch_bounds__(256) void cvt_kernel(
    const float* __restrict__ x, const float* __restrict__ base_w,
    const float* __restrict__ lora_B,
    bf16* __restrict__ Xb, bf16* __restrict__ Wb, bf16* __restrict__ Bt)
{
    const int N1V = (NTOK * DIM) / 8;   // 2,097,152 (x, 8 elems/thread)
    const int N2V = (DIM * DIM) / 8;    //   524,288 (base_w)
    int i = blockIdx.x * 256 + threadIdx.x;
    if (i < N1V) {
        const float* s = x + (size_t)i * 8;
        float4 v0 = *(const float4*)s;
        float4 v1 = *(const float4*)(s + 4);
        *(short8*)(Xb + (size_t)i * 8) = pack8(v0, v1);
    } else if (i < N1V + N2V) {
        int k = i - N1V;
        const float* s = base_w + (size_t)k * 8;
        float4 v0 = *(const float4*)s;
        float4 v1 = *(const float4*)(s + 4);
        *(short8*)(Wb + (size_t)k * 8) = pack8(v0, v1);
    } else {
        int k = i - N1V - N2V;          // < DIM*KLORA = 262,144
        int kk = k & 127, j = k >> 7;   // Bt[j][kk] = lora_B[kk][j]
        Bt[k] = __float2bfloat16(lora_B[(size_t)kk * DIM + j]);
    }
}

// ------------------------------------------------------------- router kernel
__global__ __launch_bounds__(256) void router_kernel(
    const float* __restrict__ x, const float* __restrict__ gate_w,
    const float* __restrict__ gate_b, const float* __restrict__ lora_A,
    float* __restrict__ probs, bf16* __restrict__ A2)
{
    __shared__ float xs[DIM];
    __shared__ float lg[NEXP];
    __shared__ float part[16][17];
    __shared__ float hw_s[RANK];
    const int t   = blockIdx.x;
    const int tid = threadIdx.x;
    const float* xr = x + (size_t)t * DIM;

    // stage x row (8KB) into LDS
    {
        float4 v0 = *(const float4*)(xr + tid * 8);
        float4 v1 = *(const float4*)(xr + tid * 8 + 4);
        *(float4*)(xs + tid * 8)     = v0;
        *(float4*)(xs + tid * 8 + 4) = v1;
    }
    __syncthreads();

    // logits: 32 threads per expert, interleaved d for coalescing
    {
        int e = tid >> 5, sub = tid & 31;
        const float* wr = gate_w + (size_t)e * DIM;
        float p = 0.f;
        #pragma unroll 4
        for (int s = 0; s < 64; s++) { int d = sub + 32 * s; p += xs[d] * wr[d]; }
        #pragma unroll
        for (int off = 16; off > 0; off >>= 1) p += __shfl_down(p, off);
        if (sub == 0) lg[e] = p + gate_b[e];
    }
    __syncthreads();

    // softmax + first-max argmax (redundant across threads, exact fp32)
    float l[NEXP]; float mx = -1e30f;
    #pragma unroll
    for (int e = 0; e < NEXP; e++) { l[e] = lg[e]; mx = fmaxf(mx, l[e]); }
    float sum = 0.f;
    #pragma unroll
    for (int e = 0; e < NEXP; e++) { l[e] = __expf(l[e] - mx); sum += l[e]; }
    float inv = 1.0f / sum;
    int es = 0; float best = l[0];
    #pragma unroll
    for (int e = 1; e < NEXP; e++) if (l[e] > best) { best = l[e]; es = e; }
    float w = best * inv;
    if (tid < NEXP) probs[(size_t)t * NEXP + tid] = l[tid] * inv;

    // h[16] for selected expert: 16 threads per rank r, interleaved d
    {
        int r = tid & 15, i = tid >> 4;
        const float* ar = lora_A + (size_t)es * DIM * RANK;
        float p = 0.f;
        #pragma unroll 4
        for (int s = 0; s < 128; s++) { int d = i + 16 * s; p += xs[d] * ar[d * RANK + r]; }
        part[i][r] = p;
    }
    __syncthreads();
    if (tid < RANK) {
        float h = 0.f;
        #pragma unroll
        for (int i = 0; i < 16; i++) h += part[i][tid];
        hw_s[tid] = gelu_exact(h) * w;
    }
    __syncthreads();
    // one-hot expanded LoRA-A'' row: [E*RANK] bf16, zeros except selected expert
    if (tid < KLORA) {
        int e = tid >> 4;
        A2[(size_t)t * KLORA + tid] =
            (e == es) ? __float2bfloat16(hw_s[tid & 15]) : __float2bfloat16(0.0f);
    }
}

// --------------------------------------------------------------- GEMM kernel
// NT GEMM: out[t][j] = gelu(sum_k Xb[t][k]*Wb[j][k] + b[j]) + sum_kk A2[t][kk]*Bt[j][kk]
__global__ __launch_bounds__(256) void gemm_kernel(
    const bf16* __restrict__ Xb, const bf16* __restrict__ Wb,
    const float* __restrict__ base_b,
    const bf16* __restrict__ A2, const bf16* __restrict__ Bt,
    float* __restrict__ out)
{
    __shared__ bf16 As[128 * 32];
    __shared__ bf16 Bs[128 * 32];
    const int tid  = threadIdx.x;
    const int wave = tid >> 6, lane = tid & 63;
    const int wm = wave >> 1, wn = wave & 1;
    const int m0 = blockIdx.x * 128;
    const int n0 = blockIdx.y * 128;
    const int col = lane & 15, quad = lane >> 4;

    // staging: 512 16B chunks per tile, 2 rounds of 256 threads
    const int c1 = tid + 256;
    const bf16* gA0 = Xb + (size_t)(m0 + (tid >> 2)) * DIM + (tid & 3) * 8;
    const bf16* gA1 = Xb + (size_t)(m0 + (c1  >> 2)) * DIM + (c1  & 3) * 8;
    const bf16* gB0 = Wb + (size_t)(n0 + (tid >> 2)) * DIM + (tid & 3) * 8;
    const bf16* gB1 = Wb + (size_t)(n0 + (c1  >> 2)) * DIM + (c1  & 3) * 8;
    bf16* lA0 = As + wave * 512;           // wave-uniform chunk bases
    bf16* lA1 = As + 2048 + wave * 512;
    bf16* lB0 = Bs + wave * 512;
    bf16* lB1 = Bs + 2048 + wave * 512;

    const bf16* pa = As + (wm * 64 + col) * 32 + quad * 8;
    const bf16* pb = Bs + (wn * 64 + col) * 32 + quad * 8;

    float4v acc[4][4] = {};

    for (int k0 = 0; k0 < DIM; k0 += 32) {
        __syncthreads();                   // LDS free before overwrite
        async_ld16(gA0 + k0, lA0);
        async_ld16(gA1 + k0, lA1);
        async_ld16(gB0 + k0, lB0);
        async_ld16(gB1 + k0, lB1);
        __syncthreads();                   // drains vmcnt(0) for the DMA
        short8 a[4], b[4];
        #pragma unroll
        for (int i = 0; i < 4; i++) a[i] = *(const short8*)(pa + i * 512);
        #pragma unroll
        for (int j = 0; j < 4; j++) b[j] = *(const short8*)(pb + j * 512);
        #pragma unroll
        for (int i = 0; i < 4; i++)
            #pragma unroll
            for (int j = 0; j < 4; j++)
                acc[i][j] = __builtin_amdgcn_mfma_f32_16x16x32_bf16(
                    a[i], b[j], acc[i][j], 0, 0, 0);
    }

    // epilogue 1: bias + GELU (C/D layout: row = quad*4+reg, col = lane&15)
    float bias[4];
    #pragma unroll
    for (int j = 0; j < 4; j++) bias[j] = base_b[n0 + wn * 64 + j * 16 + col];
    #pragma unroll
    for (int i = 0; i < 4; i++)
        #pragma unroll
        for (int j = 0; j < 4; j++)
            #pragma unroll
            for (int r = 0; r < 4; r++)
                acc[i][j][r] = gelu_fast(acc[i][j][r] + bias[j]);

    // epilogue 2: LoRA as K=128 MFMA extension (4 steps of K=32)
    const bf16* pea = A2 + (size_t)(m0 + wm * 64 + col) * KLORA + quad * 8;
    const bf16* peb = Bt + (size_t)(n0 + wn * 64 + col) * KLORA + quad * 8;
    #pragma unroll
    for (int ks = 0; ks < 4; ks++) {
        short8 ea[4], eb[4];
        #pragma unroll
        for (int i = 0; i < 4; i++)
            ea[i] = *(const short8*)(pea + i * 16 * KLORA + ks * 32);
        #pragma unroll
        for (int j = 0; j < 4; j++)
            eb[j] = *(const short8*)(peb + j * 16 * KLORA + ks * 32);
        #pragma unroll
        for (int i = 0; i < 4; i++)
            #pragma unroll
            for (int j = 0; j < 4; j++)
                acc[i][j] = __builtin_amdgcn_mfma_f32_16x16x32_bf16(
                    ea[i], eb[j], acc[i][j], 0, 0, 0);
    }

    // store fp32
    #pragma unroll
    for (int i = 0; i < 4; i++) {
        #pragma unroll
        for (int j = 0; j < 4; j++) {
            int tt = m0 + wm * 64 + i * 16 + quad * 4;
            int jj = n0 + wn * 64 + j * 16 + col;
            float* po = out + (size_t)tt * DIM + jj;
            #pragma unroll
            for (int r = 0; r < 4; r++) po[(size_t)r * DIM] = acc[i][j][r];
        }
    }
}

// ------------------------------------------------------------------- launch
extern "C" void kernel_launch(void* const* d_in, const int* in_sizes, int n_in,
                              void* d_out, int out_size, void* d_ws, size_t ws_size,
                              hipStream_t stream)
{
    (void)in_sizes; (void)n_in; (void)out_size; (void)ws_size;
    const float* x      = (const float*)d_in[0];
    const float* gate_w = (const float*)d_in[1];
    const float* gate_b = (const float*)d_in[2];
    const float* base_w = (const float*)d_in[3];
    const float* base_b = (const float*)d_in[4];
    const float* lora_A = (const float*)d_in[5];
    const float* lora_B = (const float*)d_in[6];

    float* out   = (float*)d_out;                    // [8192, 2048]
    float* probs = out + (size_t)NTOK * DIM;         // [8192, 8]

    // workspace layout (needs ~44.6 MB)
    char* ws = (char*)d_ws;
    bf16* Xb = (bf16*)ws;                                      // 33,554,432 B
    bf16* Wb = (bf16*)(ws + 33554432);                         //  8,388,608 B
    bf16* A2 = (bf16*)(ws + 33554432 + 8388608);               //  2,097,152 B
    bf16* Bt = (bf16*)(ws + 33554432 + 8388608 + 2097152);     //    524,288 B

    cvt_kernel<<<11264, 256, 0, stream>>>(x, base_w, lora_B, Xb, Wb, Bt);
    router_kernel<<<NTOK, 256, 0, stream>>>(x, gate_w, gate_b, lora_A, probs, A2);
    gemm_kernel<<<dim3(64, 16), 256, 0, stream>>>(Xb, Wb, base_b, A2, Bt, out);
}

// Round 2
// 310.577 us; speedup vs baseline: 1.0098x; 1.0098x over previous
//
#include <hip/hip_runtime.h>
#include <hip/hip_bf16.h>
#include <math.h>

// MoLE layer: out = gelu(x @ base_w^T + base_b) + top1_w * (gelu(x @ A[e]) @ B[e])
// probs = softmax(x @ gate_w^T + gate_b)
// T=8192 tokens, D=2048, E=8 experts, RANK=16.
//
// Pipeline:
//  k1 cvt:    fp32->bf16 convert x, base_w; transpose lora_B -> Bt[j][e*16+r],
//             lora_A -> Ab[j=e*16+r][k] (K-major for MFMA operands).
//  k2 logits: fp32 blocked [32 tok/block]: logits+softmax+argmax exact fp32;
//             probs -> d_out tail; idx/w -> ws.
//  k3 hsel:   MFMA H_all = Xb @ Ab (all experts, K=2048); epilogue selects
//             expert per token: A2[t][e*16+r] = onehot(idx)*w*gelu(H).
//  k4 gemm:   128x128 bf16 MFMA GEMM (global_load_lds w=16, BK=32, XOR-swizzled
//             LDS chunks to kill ds_read_b128 bank conflicts). Epilogue: +bias,
//             GELU, LoRA as 4 extra K=32 MFMAs from A2/Bt, store fp32.

#define DIM   2048
#define RANK  16
#define NEXP  8
#define NTOK  8192
#define KLORA 128   // NEXP*RANK

typedef __hip_bfloat16 bf16;
typedef __attribute__((ext_vector_type(8))) short short8;  // 8 bf16 = 4 VGPRs
typedef __attribute__((ext_vector_type(4))) float float4v;

typedef const __attribute__((address_space(1))) void* gptr_t;
typedef __attribute__((address_space(3))) void*       sptr_t;

__device__ __forceinline__ void async_ld16(const bf16* g, bf16* l) {
    __builtin_amdgcn_global_load_lds((gptr_t)g, (sptr_t)l, 16, 0, 0);
}

// tanh-approx GELU: |err vs erf-gelu| <= ~3e-3, well under 0.1 threshold
__device__ __forceinline__ float gelu_fast(float x) {
    float t = 0.7978845608028654f * (x + 0.044715f * x * x * x);
    t = fminf(fmaxf(t, -10.0f), 10.0f);
    float e = __expf(2.0f * t);
    float th = (e - 1.0f) / (e + 1.0f);
    return 0.5f * x * (1.0f + th);
}

__device__ __forceinline__ short8 pack8(float4 v0, float4 v1) {
    union { bf16 h[8]; short8 v; } u;
    u.h[0] = __float2bfloat16(v0.x); u.h[1] = __float2bfloat16(v0.y);
    u.h[2] = __float2bfloat16(v0.z); u.h[3] = __float2bfloat16(v0.w);
    u.h[4] = __float2bfloat16(v1.x); u.h[5] = __float2bfloat16(v1.y);
    u.h[6] = __float2bfloat16(v1.z); u.h[7] = __float2bfloat16(v1.w);
    return u.v;
}

// ---------------------------------------------------------------- cvt kernel
__global__ __launch_bounds__(256) void cvt_kernel(
    const float* __restrict__ x, const float* __restrict__ base_w,
    const float* __restrict__ lora_B, const float* __restrict__ lora_A,
    bf16* __restrict__ Xb, bf16* __restrict__ Wb,
    bf16* __restrict__ Bt, bf16* __restrict__ Ab)
{
    const int N1V = (NTOK * DIM) / 8;   // 2,097,152 (x, 8 elems/thread)
    const int N2V = (DIM * DIM) / 8;    //   524,288 (base_w)
    const int N3  = DIM * KLORA;        //   262,144 (Bt, 1 elem/thread)
    int i = blockIdx.x * 256 + threadIdx.x;
    if (i < N1V) {
        const float* s = x + (size_t)i * 8;
        float4 v0 = *(const float4*)s;
        float4 v1 = *(const float4*)(s + 4);
        *(short8*)(Xb + (size_t)i * 8) = pack8(v0, v1);
    } else if (i < N1V + N2V) {
        int k = i - N1V;
        const float* s = base_w + (size_t)k * 8;
        float4 v0 = *(const float4*)s;
        float4 v1 = *(const float4*)(s + 4);
        *(short8*)(Wb + (size_t)k * 8) = pack8(v0, v1);
    } else if (i < N1V + N2V + N3) {
        int k = i - N1V - N2V;          // Bt[j][kk] = lora_B[kk][j]
        int kk = k & 127, j = k >> 7;
        Bt[k] = __float2bfloat16(lora_B[(size_t)kk * DIM + j]);
    } else {
        int q = i - N1V - N2V - N3;     // Ab[j][k2] = lora_A[j>>4][k2][j&15]
        int j = q >> 11, k2 = q & 2047;
        Ab[q] = __float2bfloat16(lora_A[(size_t)(j >> 4) * DIM * RANK + k2 * RANK + (j & 15)]);
    }
}

// ------------------------------------------------------------- logits kernel
// 32 tokens/block; thread (t=tid>>3, e=tid&7) owns logit(t,e) in a register.
__global__ __launch_bounds__(256) void logits_kernel(
    const float* __restrict__ x, const float* __restrict__ gate_w,
    const float* __restrict__ gate_b,
    float* __restrict__ probs, int* __restrict__ idx_out, float* __restrict__ w_out)
{
    const int LP = 260;                 // padded row stride: bank offset 4*row
    __shared__ float xs[32 * LP];       // 33.3 KB
    __shared__ float wsh[8 * LP];       //  8.3 KB
    __shared__ float lg[32 * 9];
    const int tid = threadIdx.x;
    const int t0  = blockIdx.x * 32;
    const int tl  = tid >> 3;
    const int e   = tid & 7;
    float acc = 0.f;

    for (int k0 = 0; k0 < DIM; k0 += 256) {
        __syncthreads();
        #pragma unroll
        for (int r = 0; r < 8; r++) {            // stage x[32][256]
            int v = tid + 256 * r;
            int row = v >> 6, c4 = (v & 63) * 4;
            float4 val = *(const float4*)(x + (size_t)(t0 + row) * DIM + k0 + c4);
            *(float4*)(xs + row * LP + c4) = val;
        }
        #pragma unroll
        for (int r = 0; r < 2; r++) {            // stage gate_w[8][256]
            int v = tid + 256 * r;
            int row = v >> 6, c4 = (v & 63) * 4;
            float4 val = *(const float4*)(gate_w + (size_t)row * DIM + k0 + c4);
            *(float4*)(wsh + row * LP + c4) = val;
        }
        __syncthreads();
        const float* xr = xs + tl * LP;
        const float* wr = wsh + e * LP;
        #pragma unroll 8
        for (int kk = 0; kk < 256; kk += 4) {
            float4 xv = *(const float4*)(xr + kk);
            float4 wv = *(const float4*)(wr + kk);
            acc += xv.x * wv.x + xv.y * wv.y + xv.z * wv.z + xv.w * wv.w;
        }
    }
    lg[tl * 9 + e] = acc + gate_b[e];
    __syncthreads();

    if (tid < 32) {
        float l[NEXP]; float mx = -1e30f;
        #pragma unroll
        for (int k = 0; k < NEXP; k++) { l[k] = lg[tid * 9 + k]; mx = fmaxf(mx, l[k]); }
        float sum = 0.f;
        #pragma unroll
        for (int k = 0; k < NEXP; k++) { l[k] = __expf(l[k] - mx); sum += l[k]; }
        float inv = 1.0f / sum;
        int es = 0; float best = l[0];
        #pragma unroll
        for (int k = 1; k < NEXP; k++) if (l[k] > best) { best = l[k]; es = k; }
        int t = t0 + tid;
        #pragma unroll
        for (int k = 0; k < NEXP; k++) probs[(size_t)t * NEXP + k] = l[k] * inv;
        idx_out[t] = es;
        w_out[t]   = best * inv;
    }
}

// ---------------------------------------------------------------- hsel kernel
// H_all = Xb @ Ab^T-ish (NT, K=2048, N=128); epilogue: one-hot select -> A2.
__global__ __launch_bounds__(256) void hsel_kernel(
    const bf16* __restrict__ Xb, const bf16* __restrict__ Ab,
    const int* __restrict__ idx, const float* __restrict__ wsel,
    bf16* __restrict__ A2)
{
    __shared__ bf16 As[64 * 32];
    __shared__ bf16 Bs[128 * 32];
    const int tid  = threadIdx.x;
    const int wave = tid >> 6, lane = tid & 63;
    const int wm = wave >> 1, wn = wave & 1;
    const int m0 = blockIdx.x * 64;
    const int col = lane & 15, quad = lane >> 4;

    const bf16* gA  = Xb + (size_t)(m0 + (tid >> 2)) * DIM + ((tid & 3) ^ ((tid >> 3) & 3)) * 8;
    const int  c1   = tid + 256;
    const bf16* gB0 = Ab + (size_t)(tid >> 2) * DIM + ((tid & 3) ^ ((tid >> 3) & 3)) * 8;
    const bf16* gB1 = Ab + (size_t)(c1 >> 2) * DIM + ((c1 & 3) ^ ((c1 >> 3) & 3)) * 8;
    bf16* lA  = As + wave * 512;
    bf16* lB0 = Bs + wave * 512;
    bf16* lB1 = Bs + 2048 + wave * 512;

    const int xr = quad ^ ((col >> 1) & 3);
    const bf16* pa = As + (wm * 32 + col) * 32 + xr * 8;
    const bf16* pb = Bs + (wn * 64 + col) * 32 + xr * 8;

    float4v acc[2][4] = {};
    for (int k0 = 0; k0 < DIM; k0 += 32) {
        __syncthreads();
        async_ld16(gA + k0, lA);
        async_ld16(gB0 + k0, lB0);
        async_ld16(gB1 + k0, lB1);
        __syncthreads();
        short8 a[2], b[4];
        #pragma unroll
        for (int i = 0; i < 2; i++) a[i] = *(const short8*)(pa + i * 512);
        #pragma unroll
        for (int j = 0; j < 4; j++) b[j] = *(const short8*)(pb + j * 512);
        #pragma unroll
        for (int i = 0; i < 2; i++)
            #pragma unroll
            for (int j = 0; j < 4; j++)
                acc[i][j] = __builtin_amdgcn_mfma_f32_16x16x32_bf16(
                    a[i], b[j], acc[i][j], 0, 0, 0);
    }

    #pragma unroll
    for (int i = 0; i < 2; i++) {
        int rbase = m0 + wm * 32 + i * 16 + quad * 4;
        int   id4[4]; float w4[4];
        #pragma unroll
        for (int r = 0; r < 4; r++) { id4[r] = idx[rbase + r]; w4[r] = wsel[rbase + r]; }
        #pragma unroll
        for (int j = 0; j < 4; j++) {
            int jcol = wn * 64 + j * 16 + col;
            int ej = jcol >> 4;
            #pragma unroll
            for (int r = 0; r < 4; r++) {
                float v = (id4[r] == ej) ? gelu_fast(acc[i][j][r]) * w4[r] : 0.0f;
                A2[(size_t)(rbase + r) * KLORA + jcol] = __float2bfloat16(v);
            }
        }
    }
}

// --------------------------------------------------------------- GEMM kernel
__global__ __launch_bounds__(256) void gemm_kernel(
    const bf16* __restrict__ Xb, const bf16* __restrict__ Wb,
    const float* __restrict__ base_b,
    const bf16* __restrict__ A2, const bf16* __restrict__ Bt,
    float* __restrict__ out)
{
    __shared__ bf16 As[128 * 32];
    __shared__ bf16 Bs[128 * 32];
    const int tid  = threadIdx.x;
    const int wave = tid >> 6, lane = tid & 63;
    const int wm = wave >> 1, wn = wave & 1;
    const int m0 = blockIdx.x * 128;
    const int n0 = blockIdx.y * 128;
    const int col = lane & 15, quad = lane >> 4;

    // staging: 512 16B chunks/tile; chunk c holds global kchunk (c&3)^((c>>3)&3)
    // so that read-side slot = quad ^ ((row>>1)&3) spreads banks (XOR swizzle).
    const int c1 = tid + 256;
    const bf16* gA0 = Xb + (size_t)(m0 + (tid >> 2)) * DIM + ((tid & 3) ^ ((tid >> 3) & 3)) * 8;
    const bf16* gA1 = Xb + (size_t)(m0 + (c1  >> 2)) * DIM + ((c1  & 3) ^ ((c1  >> 3) & 3)) * 8;
    const bf16* gB0 = Wb + (size_t)(n0 + (tid >> 2)) * DIM + ((tid & 3) ^ ((tid >> 3) & 3)) * 8;
    const bf16* gB1 = Wb + (size_t)(n0 + (c1  >> 2)) * DIM + ((c1  & 3) ^ ((c1  >> 3) & 3)) * 8;
    bf16* lA0 = As + wave * 512;
    bf16* lA1 = As + 2048 + wave * 512;
    bf16* lB0 = Bs + wave * 512;
    bf16* lB1 = Bs + 2048 + wave * 512;

    const int xr = quad ^ ((col >> 1) & 3);
    const bf16* pa = As + (wm * 64 + col) * 32 + xr * 8;
    const bf16* pb = Bs + (wn * 64 + col) * 32 + xr * 8;

    float4v acc[4][4] = {};

    for (int k0 = 0; k0 < DIM; k0 += 32) {
        __syncthreads();
        async_ld16(gA0 + k0, lA0);
        async_ld16(gA1 + k0, lA1);
        async_ld16(gB0 + k0, lB0);
        async_ld16(gB1 + k0, lB1);
        __syncthreads();
        short8 a[4], b[4];
        #pragma unroll
        for (int i = 0; i < 4; i++) a[i] = *(const short8*)(pa + i * 512);
        #pragma unroll
        for (int j = 0; j < 4; j++) b[j] = *(const short8*)(pb + j * 512);
        #pragma unroll
        for (int i = 0; i < 4; i++)
            #pragma unroll
            for (int j = 0; j < 4; j++)
                acc[i][j] = __builtin_amdgcn_mfma_f32_16x16x32_bf16(
                    a[i], b[j], acc[i][j], 0, 0, 0);
    }

    // epilogue 1: bias + GELU (C/D: row = quad*4+reg, col = lane&15)
    float bias[4];
    #pragma unroll
    for (int j = 0; j < 4; j++) bias[j] = base_b[n0 + wn * 64 + j * 16 + col];
    #pragma unroll
    for (int i = 0; i < 4; i++)
        #pragma unroll
        for (int j = 0; j < 4; j++)
            #pragma unroll
            for (int r = 0; r < 4; r++)
                acc[i][j][r] = gelu_fast(acc[i][j][r] + bias[j]);

    // epilogue 2: LoRA as K=128 MFMA extension (4 steps of K=32)
    const bf16* pea = A2 + (size_t)(m0 + wm * 64 + col) * KLORA + quad * 8;
    const bf16* peb = Bt + (size_t)(n0 + wn * 64 + col) * KLORA + quad * 8;
    #pragma unroll
    for (int ks = 0; ks < 4; ks++) {
        short8 ea[4], eb[4];
        #pragma unroll
        for (int i = 0; i < 4; i++)
            ea[i] = *(const short8*)(pea + i * 16 * KLORA + ks * 32);
        #pragma unroll
        for (int j = 0; j < 4; j++)
            eb[j] = *(const short8*)(peb + j * 16 * KLORA + ks * 32);
        #pragma unroll
        for (int i = 0; i < 4; i++)
            #pragma unroll
            for (int j = 0; j < 4; j++)
                acc[i][j] = __builtin_amdgcn_mfma_f32_16x16x32_bf16(
                    ea[i], eb[j], acc[i][j], 0, 0, 0);
    }

    // store fp32
    #pragma unroll
    for (int i = 0; i < 4; i++) {
        #pragma unroll
        for (int j = 0; j < 4; j++) {
            int tt = m0 + wm * 64 + i * 16 + quad * 4;
            int jj = n0 + wn * 64 + j * 16 + col;
            float* po = out + (size_t)tt * DIM + jj;
            #pragma unroll
            for (int r = 0; r < 4; r++) po[(size_t)r * DIM] = acc[i][j][r];
        }
    }
}

// ------------------------------------------------------------------- launch
extern "C" void kernel_launch(void* const* d_in, const int* in_sizes, int n_in,
                              void* d_out, int out_size, void* d_ws, size_t ws_size,
                              hipStream_t stream)
{
    (void)in_sizes; (void)n_in; (void)out_size; (void)ws_size;
    const float* x      = (const float*)d_in[0];
    const float* gate_w = (const float*)d_in[1];
    const float* gate_b = (const float*)d_in[2];
    const float* base_w = (const float*)d_in[3];
    const float* base_b = (const float*)d_in[4];
    const float* lora_A = (const float*)d_in[5];
    const float* lora_B = (const float*)d_in[6];

    float* out   = (float*)d_out;                    // [8192, 2048]
    float* probs = out + (size_t)NTOK * DIM;         // [8192, 8]

    // workspace layout (~45.2 MB)
    char* ws = (char*)d_ws;
    bf16*  Xb   = (bf16*)ws;                          // 33,554,432 B
    bf16*  Wb   = (bf16*)(ws + 33554432);             //  8,388,608 B
    bf16*  A2   = (bf16*)(ws + 41943040);             //  2,097,152 B
    bf16*  Bt   = (bf16*)(ws + 44040192);             //    524,288 B
    bf16*  Ab   = (bf16*)(ws + 44564480);             //    524,288 B
    int*   idx  = (int*) (ws + 45088768);             //     32,768 B
    float* wsel = (float*)(ws + 45121536);            //     32,768 B

    cvt_kernel<<<12288, 256, 0, stream>>>(x, base_w, lora_B, lora_A, Xb, Wb, Bt, Ab);
    logits_kernel<<<NTOK / 32, 256, 0, stream>>>(x, gate_w, gate_b, probs, idx, wsel);
    hsel_kernel<<<NTOK / 64, 256, 0, stream>>>(Xb, Ab, idx, wsel, A2);
    gemm_kernel<<<dim3(64, 16), 256, 0, stream>>>(Xb, Wb, base_b, A2, Bt, out);
}

// Round 3
// 297.146 us; speedup vs baseline: 1.0554x; 1.0452x over previous
//
#include <hip/hip_runtime.h>
#include <hip/hip_bf16.h>
#include <math.h>

// MoLE layer: out = gelu(x @ base_w^T + base_b) + top1_w * (gelu(x @ A[e]) @ B[e])
// probs = softmax(x @ gate_w^T + gate_b)
// T=8192 tokens, D=2048, E=8 experts, RANK=16.
//
// Pipeline (3 kernels):
//  k1 cvt_logits: blocks 0..8191 convert token rows fp32->bf16 AND compute that
//     token's fp32 logits/softmax/argmax (gate_w L2-resident); remaining blocks
//     convert base_w and do coalesced LDS-tiled transposes of lora_B -> Bt and
//     lora_A -> Ab (K-major bf16 for MFMA operands).
//  k2 hsel: dense H = Xb @ Ab over ALL experts (K=2048) as 32x64-tile MFMA GEMM,
//     grid (256,2)=512 blocks; epilogue writes one-hot A2[t][e*16+r] =
//     (idx[t]==e) * w[t] * gelu(H).
//  k3 gemm: 128x128 bf16 MFMA GEMM (global_load_lds w=16, BK=32, XOR-swizzled
//     LDS), __launch_bounds__(256,3) to fit 3 waves/SIMD (was 172 regs -> 2).
//     Epilogue: +bias, GELU, LoRA as 4 extra K=32 MFMAs from A2/Bt, store fp32.

#define DIM   2048
#define RANK  16
#define NEXP  8
#define NTOK  8192
#define KLORA 128   // NEXP*RANK

typedef __hip_bfloat16 bf16;
typedef __attribute__((ext_vector_type(8))) short short8;  // 8 bf16 = 4 VGPRs
typedef __attribute__((ext_vector_type(4))) float float4v;

typedef const __attribute__((address_space(1))) void* gptr_t;
typedef __attribute__((address_space(3))) void*       sptr_t;

__device__ __forceinline__ void async_ld16(const bf16* g, bf16* l) {
    __builtin_amdgcn_global_load_lds((gptr_t)g, (sptr_t)l, 16, 0, 0);
}

// tanh-approx GELU: |err vs erf-gelu| <= ~3e-3, well under 0.1 threshold
__device__ __forceinline__ float gelu_fast(float x) {
    float t = 0.7978845608028654f * (x + 0.044715f * x * x * x);
    t = fminf(fmaxf(t, -10.0f), 10.0f);
    float e = __expf(2.0f * t);
    float th = (e - 1.0f) / (e + 1.0f);
    return 0.5f * x * (1.0f + th);
}

__device__ __forceinline__ short8 pack8(float4 v0, float4 v1) {
    union { bf16 h[8]; short8 v; } u;
    u.h[0] = __float2bfloat16(v0.x); u.h[1] = __float2bfloat16(v0.y);
    u.h[2] = __float2bfloat16(v0.z); u.h[3] = __float2bfloat16(v0.w);
    u.h[4] = __float2bfloat16(v1.x); u.h[5] = __float2bfloat16(v1.y);
    u.h[6] = __float2bfloat16(v1.z); u.h[7] = __float2bfloat16(v1.w);
    return u.v;
}

// --------------------------------------------------------- cvt+logits kernel
// blocks [0,8192): token cvt + logits.  [8192,10240): base_w cvt.
// [10240,10496): Bt transpose (32x32 tiles). [10496,10624): Ab transpose.
__global__ __launch_bounds__(256) void cvt_logits_kernel(
    const float* __restrict__ x, const float* __restrict__ gate_w,
    const float* __restrict__ gate_b, const float* __restrict__ base_w,
    const float* __restrict__ lora_B, const float* __restrict__ lora_A,
    bf16* __restrict__ Xb, bf16* __restrict__ Wb,
    bf16* __restrict__ Bt, bf16* __restrict__ Ab,
    float* __restrict__ probs, int* __restrict__ idx_out, float* __restrict__ w_out)
{
    __shared__ float buf[2560];         // shared scratch for all branches
    const int b   = blockIdx.x;
    const int tid = threadIdx.x;

    if (b < NTOK) {
        // ---- token convert + fp32 logits ----
        const float* xr = x + (size_t)b * DIM + tid * 8;
        float4 v0 = *(const float4*)xr;
        float4 v1 = *(const float4*)(xr + 4);
        *(short8*)(Xb + (size_t)b * DIM + tid * 8) = pack8(v0, v1);

        float acc[NEXP];
        #pragma unroll
        for (int e = 0; e < NEXP; e++) {
            const float* wr = gate_w + (size_t)e * DIM + tid * 8;
            float4 w0 = *(const float4*)wr;
            float4 w1 = *(const float4*)(wr + 4);
            acc[e] = v0.x * w0.x + v0.y * w0.y + v0.z * w0.z + v0.w * w0.w
                   + v1.x * w1.x + v1.y * w1.y + v1.z * w1.z + v1.w * w1.w;
        }
        // wave reduce (64 lanes)
        #pragma unroll
        for (int e = 0; e < NEXP; e++) {
            #pragma unroll
            for (int off = 32; off > 0; off >>= 1)
                acc[e] += __shfl_down(acc[e], off);
        }
        const int wave = tid >> 6, lane = tid & 63;
        if (lane == 0) {
            #pragma unroll
            for (int e = 0; e < NEXP; e++) buf[wave * NEXP + e] = acc[e];
        }
        __syncthreads();
        if (tid == 0) {
            float l[NEXP]; float mx = -1e30f;
            #pragma unroll
            for (int e = 0; e < NEXP; e++) {
                l[e] = buf[e] + buf[8 + e] + buf[16 + e] + buf[24 + e] + gate_b[e];
                mx = fmaxf(mx, l[e]);
            }
            float sum = 0.f;
            #pragma unroll
            for (int e = 0; e < NEXP; e++) { l[e] = __expf(l[e] - mx); sum += l[e]; }
            float inv = 1.0f / sum;
            int es = 0; float best = l[0];
            #pragma unroll
            for (int e = 1; e < NEXP; e++) if (l[e] > best) { best = l[e]; es = e; }
            #pragma unroll
            for (int e = 0; e < NEXP; e++) probs[(size_t)b * NEXP + e] = l[e] * inv;
            idx_out[b] = es;
            w_out[b]   = best * inv;
        }
    } else if (b < NTOK + 2048) {
        // ---- base_w convert: 8 floats/thread ----
        size_t v = ((size_t)(b - NTOK) * 256 + tid) * 8;
        float4 v0 = *(const float4*)(base_w + v);
        float4 v1 = *(const float4*)(base_w + v + 4);
        *(short8*)(Wb + v) = pack8(v0, v1);
    } else if (b < NTOK + 2048 + 256) {
        // ---- Bt transpose: lora_B [128][2048] -> Bt [2048][128], 32x32 tile
        int bb = b - NTOK - 2048;
        int kk0 = (bb >> 6) * 32, j0 = (bb & 63) * 32;
        {   // read coalesced along j
            int r = tid >> 3, c4 = (tid & 7) * 4;
            float4 val = *(const float4*)(lora_B + (size_t)(kk0 + r) * DIM + j0 + c4);
            *(float4*)(buf + r * 36 + c4) = val;   // stride 36: 16B-aligned, odd bank grp
        }
        __syncthreads();
        {   // write coalesced along kk
            int j = tid >> 3, k4 = (tid & 7) * 4;
            bf16* dst = Bt + (size_t)(j0 + j) * KLORA + kk0 + k4;
            #pragma unroll
            for (int i = 0; i < 4; i++) dst[i] = __float2bfloat16(buf[(k4 + i) * 36 + j]);
        }
    } else {
        // ---- Ab transpose: lora_A [8][2048][16] -> Ab [128][2048], 128k x 16r tile
        int bb = b - NTOK - 2048 - 256;
        int e = bb >> 4, k0 = (bb & 15) * 128;
        const float* src = lora_A + (size_t)e * DIM * RANK;
        {   // read coalesced along r: two sub-tiles of 64 k-rows
            int k = tid >> 2, r4 = (tid & 3) * 4;
            float4 va = *(const float4*)(src + (size_t)(k0 + k) * RANK + r4);
            float4 vb = *(const float4*)(src + (size_t)(k0 + k + 64) * RANK + r4);
            *(float4*)(buf + k * 20 + r4)        = va;  // stride 20: 16B-aligned
            *(float4*)(buf + (k + 64) * 20 + r4) = vb;
        }
        __syncthreads();
        {   // write coalesced along k: 16B per thread
            int r = tid >> 4, kx = (tid & 15) * 8;
            bf16* dst = Ab + (size_t)(e * 16 + r) * DIM + k0 + kx;
            #pragma unroll
            for (int i = 0; i < 8; i++) dst[i] = __float2bfloat16(buf[(kx + i) * 20 + r]);
        }
    }
}

// ---------------------------------------------------------------- hsel kernel
// H = Xb @ Ab (all experts, K=2048), 32x64 tile, grid (256,2) = 512 blocks.
// Epilogue: A2[t][jcol] = (idx[t]==jcol>>4) * w[t] * gelu(H).
__global__ __launch_bounds__(256) void hsel_kernel(
    const bf16* __restrict__ Xb, const bf16* __restrict__ Ab,
    const int* __restrict__ idx, const float* __restrict__ wsel,
    bf16* __restrict__ A2)
{
    __shared__ bf16 As[32 * 32];
    __shared__ bf16 Bs[64 * 32];
    const int tid  = threadIdx.x;
    const int wave = tid >> 6, lane = tid & 63;
    const int m0 = blockIdx.x * 32;
    const int n0 = blockIdx.y * 64;
    const int col = lane & 15, quad = lane >> 4;

    const int kc = ((tid & 3) ^ ((tid >> 3) & 3)) * 8;
    const bf16* gB = Ab + (size_t)(n0 + (tid >> 2)) * DIM + kc;
    const bf16* gA = Xb + (size_t)(m0 + (tid >> 2)) * DIM + kc;   // tid<128 only
    bf16* lB = Bs + wave * 512;
    bf16* lA = As + wave * 512;

    const int xr = quad ^ ((col >> 1) & 3);
    const bf16* pa = As + col * 32 + xr * 8;
    const bf16* pb = Bs + (wave * 16 + col) * 32 + xr * 8;

    float4v acc[2] = {};
    for (int k0 = 0; k0 < DIM; k0 += 32) {
        __syncthreads();
        async_ld16(gB + k0, lB);
        if (tid < 128) async_ld16(gA + k0, lA);
        __syncthreads();
        short8 a0 = *(const short8*)pa;
        short8 a1 = *(const short8*)(pa + 512);
        short8 b0 = *(const short8*)pb;
        acc[0] = __builtin_amdgcn_mfma_f32_16x16x32_bf16(a0, b0, acc[0], 0, 0, 0);
        acc[1] = __builtin_amdgcn_mfma_f32_16x16x32_bf16(a1, b0, acc[1], 0, 0, 0);
    }

    const int jcol = n0 + wave * 16 + col;
    const int ej   = jcol >> 4;
    #pragma unroll
    for (int i = 0; i < 2; i++) {
        int rbase = m0 + i * 16 + quad * 4;
        #pragma unroll
        for (int r = 0; r < 4; r++) {
            int t = rbase + r;
            float v = (idx[t] == ej) ? gelu_fast(acc[i][r]) * wsel[t] : 0.0f;
            A2[(size_t)t * KLORA + jcol] = __float2bfloat16(v);
        }
    }
}

// --------------------------------------------------------------- GEMM kernel
__global__ __launch_bounds__(256, 3) void gemm_kernel(
    const bf16* __restrict__ Xb, const bf16* __restrict__ Wb,
    const float* __restrict__ base_b,
    const bf16* __restrict__ A2, const bf16* __restrict__ Bt,
    float* __restrict__ out)
{
    __shared__ bf16 As[128 * 32];
    __shared__ bf16 Bs[128 * 32];
    const int tid  = threadIdx.x;
    const int wave = tid >> 6, lane = tid & 63;
    const int wm = wave >> 1, wn = wave & 1;
    const int m0 = blockIdx.x * 128;
    const int n0 = blockIdx.y * 128;
    const int col = lane & 15, quad = lane >> 4;

    // staging: 512 16B chunks/tile; XOR-swizzled k-chunk slots (read-side
    // slot = quad ^ ((row>>1)&3) -> conflict-free ds_read_b128)
    const int kc = ((tid & 3) ^ ((tid >> 3) & 3)) * 8;
    const bf16* gA0 = Xb + (size_t)(m0 + (tid >> 2)) * DIM + kc;
    const bf16* gB0 = Wb + (size_t)(n0 + (tid >> 2)) * DIM + kc;
    const bf16* gA1 = gA0 + (size_t)64 * DIM;     // chunk tid+256: row+64, same kc
    const bf16* gB1 = gB0 + (size_t)64 * DIM;
    bf16* lA0 = As + wave * 512;
    bf16* lA1 = lA0 + 2048;
    bf16* lB0 = Bs + wave * 512;
    bf16* lB1 = lB0 + 2048;

    const int xr = quad ^ ((col >> 1) & 3);
    const bf16* pa = As + (wm * 64 + col) * 32 + xr * 8;
    const bf16* pb = Bs + (wn * 64 + col) * 32 + xr * 8;

    float4v acc[4][4] = {};

    for (int k0 = 0; k0 < DIM; k0 += 32) {
        __syncthreads();
        async_ld16(gA0 + k0, lA0);
        async_ld16(gA1 + k0, lA1);
        async_ld16(gB0 + k0, lB0);
        async_ld16(gB1 + k0, lB1);
        __syncthreads();
        short8 a[4], b[4];
        #pragma unroll
        for (int i = 0; i < 4; i++) a[i] = *(const short8*)(pa + i * 512);
        #pragma unroll
        for (int j = 0; j < 4; j++) b[j] = *(const short8*)(pb + j * 512);
        #pragma unroll
        for (int i = 0; i < 4; i++)
            #pragma unroll
            for (int j = 0; j < 4; j++)
                acc[i][j] = __builtin_amdgcn_mfma_f32_16x16x32_bf16(
                    a[i], b[j], acc[i][j], 0, 0, 0);
    }

    // epilogue 1: bias + GELU (C/D: row = quad*4+reg, col = lane&15)
    float bias[4];
    #pragma unroll
    for (int j = 0; j < 4; j++) bias[j] = base_b[n0 + wn * 64 + j * 16 + col];
    #pragma unroll
    for (int i = 0; i < 4; i++)
        #pragma unroll
        for (int j = 0; j < 4; j++)
            #pragma unroll
            for (int r = 0; r < 4; r++)
                acc[i][j][r] = gelu_fast(acc[i][j][r] + bias[j]);

    // epilogue 2: LoRA as K=128 MFMA extension (4 steps of K=32)
    const bf16* pea = A2 + (size_t)(m0 + wm * 64 + col) * KLORA + quad * 8;
    const bf16* peb = Bt + (size_t)(n0 + wn * 64 + col) * KLORA + quad * 8;
    #pragma unroll
    for (int ks = 0; ks < 4; ks++) {
        short8 ea[4], eb[4];
        #pragma unroll
        for (int i = 0; i < 4; i++)
            ea[i] = *(const short8*)(pea + i * 16 * KLORA + ks * 32);
        #pragma unroll
        for (int j = 0; j < 4; j++)
            eb[j] = *(const short8*)(peb + j * 16 * KLORA + ks * 32);
        #pragma unroll
        for (int i = 0; i < 4; i++)
            #pragma unroll
            for (int j = 0; j < 4; j++)
                acc[i][j] = __builtin_amdgcn_mfma_f32_16x16x32_bf16(
                    ea[i], eb[j], acc[i][j], 0, 0, 0);
    }

    // store fp32
    #pragma unroll
    for (int i = 0; i < 4; i++) {
        #pragma unroll
        for (int j = 0; j < 4; j++) {
            int tt = m0 + wm * 64 + i * 16 + quad * 4;
            int jj = n0 + wn * 64 + j * 16 + col;
            float* po = out + (size_t)tt * DIM + jj;
            #pragma unroll
            for (int r = 0; r < 4; r++) po[(size_t)r * DIM] = acc[i][j][r];
        }
    }
}

// ------------------------------------------------------------------- launch
extern "C" void kernel_launch(void* const* d_in, const int* in_sizes, int n_in,
                              void* d_out, int out_size, void* d_ws, size_t ws_size,
                              hipStream_t stream)
{
    (void)in_sizes; (void)n_in; (void)out_size; (void)ws_size;
    const float* x      = (const float*)d_in[0];
    const float* gate_w = (const float*)d_in[1];
    const float* gate_b = (const float*)d_in[2];
    const float* base_w = (const float*)d_in[3];
    const float* base_b = (const float*)d_in[4];
    const float* lora_A = (const float*)d_in[5];
    const float* lora_B = (const float*)d_in[6];

    float* out   = (float*)d_out;                    // [8192, 2048]
    float* probs = out + (size_t)NTOK * DIM;         // [8192, 8]

    // workspace layout (~45.2 MB)
    char* ws = (char*)d_ws;
    bf16*  Xb   = (bf16*)ws;                          // 33,554,432 B
    bf16*  Wb   = (bf16*)(ws + 33554432);             //  8,388,608 B
    bf16*  A2   = (bf16*)(ws + 41943040);             //  2,097,152 B
    bf16*  Bt   = (bf16*)(ws + 44040192);             //    524,288 B
    bf16*  Ab   = (bf16*)(ws + 44564480);             //    524,288 B
    int*   idx  = (int*) (ws + 45088768);             //     32,768 B
    float* wsel = (float*)(ws + 45121536);            //     32,768 B

    cvt_logits_kernel<<<NTOK + 2048 + 256 + 128, 256, 0, stream>>>(
        x, gate_w, gate_b, base_w, lora_B, lora_A,
        Xb, Wb, Bt, Ab, probs, idx, wsel);
    hsel_kernel<<<dim3(256, 2), 256, 0, stream>>>(Xb, Ab, idx, wsel, A2);
    gemm_kernel<<<dim3(64, 16), 256, 0, stream>>>(Xb, Wb, base_b, A2, Bt, out);
}

// Round 4
// 253.182 us; speedup vs baseline: 1.2387x; 1.1736x over previous
//
#include <hip/hip_runtime.h>
#include <hip/hip_bf16.h>
#include <math.h>

// MoLE layer: out = gelu(x @ base_w^T + base_b) + top1_w * (gelu(x @ A[e]) @ B[e])
// probs = softmax(x @ gate_w^T + gate_b)
// T=8192 tokens, D=2048, E=8 experts, RANK=16.
//
// Pipeline (3 kernels):
//  k1 cvt_logits: token blocks (8 tokens each) convert x fp32->bf16 AND compute
//     fp32 logits/softmax/argmax with gate_w cached in REGISTERS (read once per
//     block -> 64 MB L2 instead of 512 MB); other blocks convert base_w and do
//     LDS-tiled transposes lora_B -> Bt, lora_A -> Ab (K-major bf16).
//  k2 hsel: dense H = Xb @ Ab over ALL experts (K=2048), 32x64 tiles, grid
//     (256,2); epilogue writes one-hot A2[t][e*16+r] = (idx==e)*w*gelu(H).
//  k3 gemm: 128x128 bf16 MFMA GEMM, BK=64 staging (halves barrier-drain count
//     vs BK=32; two K=32 passes per buffer keep VGPRs at 3-waves/SIMD level),
//     8-slot XOR-swizzled LDS (conflict-free ds_read_b128), n-fastest grid for
//     L2 (Wb slab + 16 m-slabs fit 16 MB). Epilogue: +bias, GELU, LoRA as 4
//     extra K=32 MFMAs from A2/Bt, store fp32.

#define DIM   2048
#define RANK  16
#define NEXP  8
#define NTOK  8192
#define KLORA 128   // NEXP*RANK

typedef __hip_bfloat16 bf16;
typedef __attribute__((ext_vector_type(8))) short short8;  // 8 bf16 = 4 VGPRs
typedef __attribute__((ext_vector_type(4))) float float4v;

typedef const __attribute__((address_space(1))) void* gptr_t;
typedef __attribute__((address_space(3))) void*       sptr_t;

__device__ __forceinline__ void async_ld16(const bf16* g, bf16* l) {
    __builtin_amdgcn_global_load_lds((gptr_t)g, (sptr_t)l, 16, 0, 0);
}

// tanh-approx GELU: |err vs erf-gelu| <= ~3e-3, well under 0.1 threshold
__device__ __forceinline__ float gelu_fast(float x) {
    float t = 0.7978845608028654f * (x + 0.044715f * x * x * x);
    t = fminf(fmaxf(t, -10.0f), 10.0f);
    float e = __expf(2.0f * t);
    float th = (e - 1.0f) / (e + 1.0f);
    return 0.5f * x * (1.0f + th);
}

__device__ __forceinline__ short8 pack8(float4 v0, float4 v1) {
    union { bf16 h[8]; short8 v; } u;
    u.h[0] = __float2bfloat16(v0.x); u.h[1] = __float2bfloat16(v0.y);
    u.h[2] = __float2bfloat16(v0.z); u.h[3] = __float2bfloat16(v0.w);
    u.h[4] = __float2bfloat16(v1.x); u.h[5] = __float2bfloat16(v1.y);
    u.h[6] = __float2bfloat16(v1.z); u.h[7] = __float2bfloat16(v1.w);
    return u.v;
}

// --------------------------------------------------------- cvt+logits kernel
// blocks [0,1024): 8 tokens each, cvt + fp32 logits (gate_w in registers).
// [1024,3072): base_w cvt.  [3072,3328): Bt transpose.  [3328,3456): Ab transp.
__global__ __launch_bounds__(256) void cvt_logits_kernel(
    const float* __restrict__ x, const float* __restrict__ gate_w,
    const float* __restrict__ gate_b, const float* __restrict__ base_w,
    const float* __restrict__ lora_B, const float* __restrict__ lora_A,
    bf16* __restrict__ Xb, bf16* __restrict__ Wb,
    bf16* __restrict__ Bt, bf16* __restrict__ Ab,
    float* __restrict__ probs, int* __restrict__ idx_out, float* __restrict__ w_out)
{
    __shared__ float buf[2560];         // shared scratch for all branches
    const int b   = blockIdx.x;
    const int tid = threadIdx.x;

    if (b < 1024) {
        // ---- 8 tokens: convert + fp32 logits ----
        const int t0 = b * 8;
        float4 g0[NEXP], g1[NEXP];      // gate_w slice: 8 experts x 8 floats
        #pragma unroll
        for (int e = 0; e < NEXP; e++) {
            const float* wr = gate_w + (size_t)e * DIM + tid * 8;
            g0[e] = *(const float4*)wr;
            g1[e] = *(const float4*)(wr + 4);
        }
        const int wave = tid >> 6, lane = tid & 63;
        #pragma unroll
        for (int tt = 0; tt < 8; tt++) {
            const int t = t0 + tt;
            const float* xr = x + (size_t)t * DIM + tid * 8;
            float4 v0 = *(const float4*)xr;
            float4 v1 = *(const float4*)(xr + 4);
            *(short8*)(Xb + (size_t)t * DIM + tid * 8) = pack8(v0, v1);
            float a[NEXP];
            #pragma unroll
            for (int e = 0; e < NEXP; e++) {
                a[e] = v0.x * g0[e].x + v0.y * g0[e].y + v0.z * g0[e].z + v0.w * g0[e].w
                     + v1.x * g1[e].x + v1.y * g1[e].y + v1.z * g1[e].z + v1.w * g1[e].w;
                #pragma unroll
                for (int off = 32; off > 0; off >>= 1) a[e] += __shfl_down(a[e], off);
            }
            if (lane == 0) {
                #pragma unroll
                for (int e = 0; e < NEXP; e++) buf[tt * 32 + wave * NEXP + e] = a[e];
            }
        }
        __syncthreads();
        if (tid < 8) {                  // thread tid finalizes token t0+tid
            const int t = t0 + tid;
            float l[NEXP]; float mx = -1e30f;
            #pragma unroll
            for (int e = 0; e < NEXP; e++) {
                l[e] = buf[tid * 32 + e] + buf[tid * 32 + 8 + e]
                     + buf[tid * 32 + 16 + e] + buf[tid * 32 + 24 + e] + gate_b[e];
                mx = fmaxf(mx, l[e]);
            }
            float sum = 0.f;
            #pragma unroll
            for (int e = 0; e < NEXP; e++) { l[e] = __expf(l[e] - mx); sum += l[e]; }
            float inv = 1.0f / sum;
            int es = 0; float best = l[0];
            #pragma unroll
            for (int e = 1; e < NEXP; e++) if (l[e] > best) { best = l[e]; es = e; }
            #pragma unroll
            for (int e = 0; e < NEXP; e++) probs[(size_t)t * NEXP + e] = l[e] * inv;
            idx_out[t] = es;
            w_out[t]   = best * inv;
        }
    } else if (b < 1024 + 2048) {
        // ---- base_w convert: 8 floats/thread ----
        size_t v = ((size_t)(b - 1024) * 256 + tid) * 8;
        float4 v0 = *(const float4*)(base_w + v);
        float4 v1 = *(const float4*)(base_w + v + 4);
        *(short8*)(Wb + v) = pack8(v0, v1);
    } else if (b < 1024 + 2048 + 256) {
        // ---- Bt transpose: lora_B [128][2048] -> Bt [2048][128], 32x32 tile
        int bb = b - 1024 - 2048;
        int kk0 = (bb >> 6) * 32, j0 = (bb & 63) * 32;
        {   // read coalesced along j
            int r = tid >> 3, c4 = (tid & 7) * 4;
            float4 val = *(const float4*)(lora_B + (size_t)(kk0 + r) * DIM + j0 + c4);
            *(float4*)(buf + r * 36 + c4) = val;
        }
        __syncthreads();
        {   // write coalesced along kk
            int j = tid >> 3, k4 = (tid & 7) * 4;
            bf16* dst = Bt + (size_t)(j0 + j) * KLORA + kk0 + k4;
            #pragma unroll
            for (int i = 0; i < 4; i++) dst[i] = __float2bfloat16(buf[(k4 + i) * 36 + j]);
        }
    } else {
        // ---- Ab transpose: lora_A [8][2048][16] -> Ab [128][2048]
        int bb = b - 1024 - 2048 - 256;
        int e = bb >> 4, k0 = (bb & 15) * 128;
        const float* src = lora_A + (size_t)e * DIM * RANK;
        {
            int k = tid >> 2, r4 = (tid & 3) * 4;
            float4 va = *(const float4*)(src + (size_t)(k0 + k) * RANK + r4);
            float4 vb = *(const float4*)(src + (size_t)(k0 + k + 64) * RANK + r4);
            *(float4*)(buf + k * 20 + r4)        = va;
            *(float4*)(buf + (k + 64) * 20 + r4) = vb;
        }
        __syncthreads();
        {
            int r = tid >> 4, kx = (tid & 15) * 8;
            bf16* dst = Ab + (size_t)(e * 16 + r) * DIM + k0 + kx;
            #pragma unroll
            for (int i = 0; i < 8; i++) dst[i] = __float2bfloat16(buf[(kx + i) * 20 + r]);
        }
    }
}

// ---------------------------------------------------------------- hsel kernel
// H = Xb @ Ab (all experts, K=2048), 32x64 tile, grid (256,2) = 512 blocks.
// Epilogue: A2[t][jcol] = (idx[t]==jcol>>4) * w[t] * gelu(H).
__global__ __launch_bounds__(256) void hsel_kernel(
    const bf16* __restrict__ Xb, const bf16* __restrict__ Ab,
    const int* __restrict__ idx, const float* __restrict__ wsel,
    bf16* __restrict__ A2)
{
    __shared__ bf16 As[32 * 32];
    __shared__ bf16 Bs[64 * 32];
    const int tid  = threadIdx.x;
    const int wave = tid >> 6, lane = tid & 63;
    const int m0 = blockIdx.x * 32;
    const int n0 = blockIdx.y * 64;
    const int col = lane & 15, quad = lane >> 4;

    const int kc = ((tid & 3) ^ ((tid >> 3) & 3)) * 8;
    const bf16* gB = Ab + (size_t)(n0 + (tid >> 2)) * DIM + kc;
    const bf16* gA = Xb + (size_t)(m0 + (tid >> 2)) * DIM + kc;   // tid<128 only
    bf16* lB = Bs + wave * 512;
    bf16* lA = As + wave * 512;

    const int xr = quad ^ ((col >> 1) & 3);
    const bf16* pa = As + col * 32 + xr * 8;
    const bf16* pb = Bs + (wave * 16 + col) * 32 + xr * 8;

    float4v acc[2] = {};
    for (int k0 = 0; k0 < DIM; k0 += 32) {
        __syncthreads();
        async_ld16(gB + k0, lB);
        if (tid < 128) async_ld16(gA + k0, lA);
        __syncthreads();
        short8 a0 = *(const short8*)pa;
        short8 a1 = *(const short8*)(pa + 512);
        short8 b0 = *(const short8*)pb;
        acc[0] = __builtin_amdgcn_mfma_f32_16x16x32_bf16(a0, b0, acc[0], 0, 0, 0);
        acc[1] = __builtin_amdgcn_mfma_f32_16x16x32_bf16(a1, b0, acc[1], 0, 0, 0);
    }

    const int jcol = n0 + wave * 16 + col;
    const int ej   = jcol >> 4;
    #pragma unroll
    for (int i = 0; i < 2; i++) {
        int rbase = m0 + i * 16 + quad * 4;
        #pragma unroll
        for (int r = 0; r < 4; r++) {
            int t = rbase + r;
            float v = (idx[t] == ej) ? gelu_fast(acc[i][r]) * wsel[t] : 0.0f;
            A2[(size_t)t * KLORA + jcol] = __float2bfloat16(v);
        }
    }
}

// --------------------------------------------------------------- GEMM kernel
// BK=64 staging (32 barrier rounds), two K=32 MFMA passes per staged buffer.
__global__ __launch_bounds__(256, 3) void gemm_kernel(
    const bf16* __restrict__ Xb, const bf16* __restrict__ Wb,
    const float* __restrict__ base_b,
    const bf16* __restrict__ A2, const bf16* __restrict__ Bt,
    float* __restrict__ out)
{
    __shared__ bf16 As[128 * 64];   // 16 KB
    __shared__ bf16 Bs[128 * 64];   // 16 KB
    const int tid  = threadIdx.x;
    const int wave = tid >> 6, lane = tid & 63;
    const int wm = wave >> 1, wn = wave & 1;
    const int n0 = blockIdx.x * 128;    // n fastest: Wb slab + 16 m-slabs fit L2
    const int m0 = blockIdx.y * 128;
    const int col = lane & 15, quad = lane >> 4;

    // staging: 1024 16B chunks per tile, 4 rounds of 256 threads.
    // LDS slot (tid&7) of row (tid>>3)+32u holds global k-chunk (tid&7)^((tid>>3)&7)
    const int kc = (((tid & 7) ^ ((tid >> 3) & 7))) * 8;
    const int r0 = tid >> 3;            // 0..31
    const bf16* gA0 = Xb + (size_t)(m0 + r0) * DIM + kc;
    const bf16* gB0 = Wb + (size_t)(n0 + r0) * DIM + kc;
    const bf16* gA1 = gA0 + (size_t)32 * DIM;
    const bf16* gB1 = gB0 + (size_t)32 * DIM;
    const bf16* gA2 = gA0 + (size_t)64 * DIM;
    const bf16* gB2 = gB0 + (size_t)64 * DIM;
    const bf16* gA3 = gA0 + (size_t)96 * DIM;
    const bf16* gB3 = gB0 + (size_t)96 * DIM;
    bf16* lA = As + wave * 512;         // +2048 per round
    bf16* lB = Bs + wave * 512;

    // frag read: row = wm*64+i*16+col (row&7 == col&7); slot = (4s+quad)^(col&7)
    const int sl0 = (quad        ^ (col & 7)) * 8;
    const int sl1 = ((quad | 4)  ^ (col & 7)) * 8;
    const bf16* paA = As + (wm * 64 + col) * 64;
    const bf16* pbB = Bs + (wn * 64 + col) * 64;

    float4v acc[4][4] = {};

    for (int k0 = 0; k0 < DIM; k0 += 64) {
        __syncthreads();
        async_ld16(gA0 + k0, lA);
        async_ld16(gA1 + k0, lA + 2048);
        async_ld16(gA2 + k0, lA + 4096);
        async_ld16(gA3 + k0, lA + 6144);
        async_ld16(gB0 + k0, lB);
        async_ld16(gB1 + k0, lB + 2048);
        async_ld16(gB2 + k0, lB + 4096);
        async_ld16(gB3 + k0, lB + 6144);
        __syncthreads();
        {   // K-step 0 (k0 .. k0+32)
            short8 a[4], b[4];
            #pragma unroll
            for (int i = 0; i < 4; i++) a[i] = *(const short8*)(paA + i * 1024 + sl0);
            #pragma unroll
            for (int j = 0; j < 4; j++) b[j] = *(const short8*)(pbB + j * 1024 + sl0);
            #pragma unroll
            for (int i = 0; i < 4; i++)
                #pragma unroll
                for (int j = 0; j < 4; j++)
                    acc[i][j] = __builtin_amdgcn_mfma_f32_16x16x32_bf16(
                        a[i], b[j], acc[i][j], 0, 0, 0);
        }
        {   // K-step 1 (k0+32 .. k0+64)
            short8 a[4], b[4];
            #pragma unroll
            for (int i = 0; i < 4; i++) a[i] = *(const short8*)(paA + i * 1024 + sl1);
            #pragma unroll
            for (int j = 0; j < 4; j++) b[j] = *(const short8*)(pbB + j * 1024 + sl1);
            #pragma unroll
            for (int i = 0; i < 4; i++)
                #pragma unroll
                for (int j = 0; j < 4; j++)
                    acc[i][j] = __builtin_amdgcn_mfma_f32_16x16x32_bf16(
                        a[i], b[j], acc[i][j], 0, 0, 0);
        }
    }

    // epilogue 1: bias + GELU (C/D: row = quad*4+reg, col = lane&15)
    float bias[4];
    #pragma unroll
    for (int j = 0; j < 4; j++) bias[j] = base_b[n0 + wn * 64 + j * 16 + col];
    #pragma unroll
    for (int i = 0; i < 4; i++)
        #pragma unroll
        for (int j = 0; j < 4; j++)
            #pragma unroll
            for (int r = 0; r < 4; r++)
                acc[i][j][r] = gelu_fast(acc[i][j][r] + bias[j]);

    // epilogue 2: LoRA as K=128 MFMA extension (4 steps of K=32)
    const bf16* pea = A2 + (size_t)(m0 + wm * 64 + col) * KLORA + quad * 8;
    const bf16* peb = Bt + (size_t)(n0 + wn * 64 + col) * KLORA + quad * 8;
    #pragma unroll
    for (int ks = 0; ks < 4; ks++) {
        short8 ea[4], eb[4];
        #pragma unroll
        for (int i = 0; i < 4; i++)
            ea[i] = *(const short8*)(pea + i * 16 * KLORA + ks * 32);
        #pragma unroll
        for (int j = 0; j < 4; j++)
            eb[j] = *(const short8*)(peb + j * 16 * KLORA + ks * 32);
        #pragma unroll
        for (int i = 0; i < 4; i++)
            #pragma unroll
            for (int j = 0; j < 4; j++)
                acc[i][j] = __builtin_amdgcn_mfma_f32_16x16x32_bf16(
                    ea[i], eb[j], acc[i][j], 0, 0, 0);
    }

    // store fp32
    #pragma unroll
    for (int i = 0; i < 4; i++) {
        #pragma unroll
        for (int j = 0; j < 4; j++) {
            int tt = m0 + wm * 64 + i * 16 + quad * 4;
            int jj = n0 + wn * 64 + j * 16 + col;
            float* po = out + (size_t)tt * DIM + jj;
            #pragma unroll
            for (int r = 0; r < 4; r++) po[(size_t)r * DIM] = acc[i][j][r];
        }
    }
}

// ------------------------------------------------------------------- launch
extern "C" void kernel_launch(void* const* d_in, const int* in_sizes, int n_in,
                              void* d_out, int out_size, void* d_ws, size_t ws_size,
                              hipStream_t stream)
{
    (void)in_sizes; (void)n_in; (void)out_size; (void)ws_size;
    const float* x      = (const float*)d_in[0];
    const float* gate_w = (const float*)d_in[1];
    const float* gate_b = (const float*)d_in[2];
    const float* base_w = (const float*)d_in[3];
    const float* base_b = (const float*)d_in[4];
    const float* lora_A = (const float*)d_in[5];
    const float* lora_B = (const float*)d_in[6];

    float* out   = (float*)d_out;                    // [8192, 2048]
    float* probs = out + (size_t)NTOK * DIM;         // [8192, 8]

    // workspace layout (~45.2 MB)
    char* ws = (char*)d_ws;
    bf16*  Xb   = (bf16*)ws;                          // 33,554,432 B
    bf16*  Wb   = (bf16*)(ws + 33554432);             //  8,388,608 B
    bf16*  A2   = (bf16*)(ws + 41943040);             //  2,097,152 B
    bf16*  Bt   = (bf16*)(ws + 44040192);             //    524,288 B
    bf16*  Ab   = (bf16*)(ws + 44564480);             //    524,288 B
    int*   idx  = (int*) (ws + 45088768);             //     32,768 B
    float* wsel = (float*)(ws + 45121536);            //     32,768 B

    cvt_logits_kernel<<<1024 + 2048 + 256 + 128, 256, 0, stream>>>(
        x, gate_w, gate_b, base_w, lora_B, lora_A,
        Xb, Wb, Bt, Ab, probs, idx, wsel);
    hsel_kernel<<<dim3(256, 2), 256, 0, stream>>>(Xb, Ab, idx, wsel, A2);
    gemm_kernel<<<dim3(16, 64), 256, 0, stream>>>(Xb, Wb, base_b, A2, Bt, out);
}